// Round 11
// baseline (726.672 us; speedup 1.0000x reference)
//
#include <hip/hip_runtime.h>
#include <math.h>

// Problem sizes (fixed by setup_inputs)
constexpr int N_V  = 16384;       // original vertices
constexpr int N_F  = 16384;       // original faces (targets for fwd)
constexpr int G_F  = 8192;        // simplified faces (queries for fwd)
constexpr int NS   = 16;          // samples per face
constexpr int NPTS = G_F * NS;    // 131072 sample points (queries for rev)

constexpr int MB    = 2;          // 32-row query blocks per wave (64 queries/wave)
constexpr int TILES = 32;         // B-tiles staged per LDS chunk (32 KB)

typedef _Float16 half8 __attribute__((ext_vector_type(8)));
typedef float    f32x16 __attribute__((ext_vector_type(16)));

// ---------------- workspace layout (float4 units first, 16B aligned) ----------
constexpr int F4_ACC   = 0;                    // 1  float4: accumulators
constexpr int F4_SB    = 1;                    // [G_F]  simp barycenters x,y,z,|b|^2
constexpr int F4_PTS   = F4_SB + G_F;          // [NPTS] sample points    x,y,z,|p|^2
constexpr int F4_PKV   = F4_PTS + NPTS;        // packed verts: 512 tiles * 64 * 16B
constexpr int F4_PKO   = F4_PKV + 32768;       // packed obary: 512 tiles * 64 * 16B
constexpr int F4_TOTAL = F4_PKO + 32768;
constexpr int WS_MINF  = F4_TOTAL * 4;         // [G_F]  fwd min d^2 (uint bits)
constexpr int WS_MINR  = WS_MINF + G_F;        // [NPTS] rev min d^2 (uint bits)

// 4 MFMAs of one tile-pair in ONE asm block, dsts forced to arch VGPRs via
// "=&v", + 6 x s_nop 7 (48-cycle) hazard pad — the round-7-PROVEN core
// (round 6 unpadded: absmax 454; round 7 this exact block: absmax 0,
// 102.7 us rev).  Inline asm is opaque to the XDL hazard recognizer, so the
// pad covers the MFMA-write -> VALU-read distance for the last MFMA.
// NOTE (rounds 8-10): do NOT hard-pin dst ranges and do NOT anchor rm —
// both leave VALU time unchanged (~50 us) and only add serialization.
__device__ __forceinline__ void mfma4(half8 a0, half8 a1, half8 cA, half8 cB,
                                      f32x16& d0A, f32x16& d0B,
                                      f32x16& d1A, f32x16& d1B) {
  asm("v_mfma_f32_32x32x16_f16 %0, %4, %6, 0\n\t"
      "v_mfma_f32_32x32x16_f16 %1, %4, %7, 0\n\t"
      "v_mfma_f32_32x32x16_f16 %2, %5, %6, 0\n\t"
      "v_mfma_f32_32x32x16_f16 %3, %5, %7, 0\n\t"
      "s_nop 7\n\t"
      "s_nop 7\n\t"
      "s_nop 7\n\t"
      "s_nop 7\n\t"
      "s_nop 7\n\t"
      "s_nop 7"
      : "=&v"(d0A), "=&v"(d0B), "=&v"(d1A), "=&v"(d1B)
      : "v"(a0), "v"(a1), "v"(cA), "v"(cB));
}

// Pack one target (x,y,z,sq) into B-fragment order (validated: absmax=0):
// col n = lane&31, k = (lane>>5)*8 + j.
// k0-3 = hi(-2x,-2y,-2z,|v|^2), k4-7 = lo residuals, k8-11 = hi again, k12-15 = 0.
__device__ __forceinline__ void pack_target(float x, float y, float z, float sq,
                                            half8* __restrict__ pk, int tile, int n) {
  float ax = -2.0f*x, ay = -2.0f*y, az = -2.0f*z;
  _Float16 hx = (_Float16)ax, hy = (_Float16)ay, hz = (_Float16)az, hw = (_Float16)sq;
  _Float16 lx = (_Float16)(ax - (float)hx), ly = (_Float16)(ay - (float)hy);
  _Float16 lz = (_Float16)(az - (float)hz), lw = (_Float16)(sq - (float)hw);
  half8 h0; h0[0]=hx; h0[1]=hy; h0[2]=hz; h0[3]=hw; h0[4]=lx; h0[5]=ly; h0[6]=lz; h0[7]=lw;
  half8 h1; h1[0]=hx; h1[1]=hy; h1[2]=hz; h1[3]=hw;
  h1[4]=(_Float16)0.0f; h1[5]=(_Float16)0.0f; h1[6]=(_Float16)0.0f; h1[7]=(_Float16)0.0f;
  pk[(size_t)tile*64 + n]      = h0;
  pk[(size_t)tile*64 + 32 + n] = h1;
}

// Fused prep, one thread per sample point.
__global__ void k_prep(const float* __restrict__ ov, const int* __restrict__ of,
                       const float* __restrict__ sv, const int* __restrict__ sf,
                       const float* __restrict__ r1, const float* __restrict__ r2,
                       unsigned int* __restrict__ ws, float4* __restrict__ ws4) {
  int i = blockIdx.x * blockDim.x + threadIdx.x;
  if (i < 4) ws[i] = 0u;                          // acc = 0.0f
  ws[WS_MINR + i] = 0x7f800000u;                  // +inf (grid == NPTS exactly)

  { // sample point i (face verts are 96 KB total -> L1/L2-hot gathers)
    int g = i >> 4;
    int a = sf[3*g], b = sf[3*g+1], c = sf[3*g+2];
    float sr = sqrtf(r1[i]);
    float u = 1.0f - sr;
    float v = sr * (1.0f - r2[i]);
    float w = sr * r2[i];
    float px = u*sv[3*a]   + v*sv[3*b]   + w*sv[3*c];
    float py = u*sv[3*a+1] + v*sv[3*b+1] + w*sv[3*c+1];
    float pz = u*sv[3*a+2] + v*sv[3*b+2] + w*sv[3*c+2];
    (ws4 + F4_PTS)[i] = make_float4(px, py, pz, fmaf(px, px, fmaf(py, py, pz*pz)));
  }
  if (i < G_F) { // simp barycenter (fwd query) + minf init
    ws[WS_MINF + i] = 0x7f800000u;
    int a = sf[3*i], b = sf[3*i+1], c = sf[3*i+2];
    float x = (sv[3*a] + sv[3*b] + sv[3*c]) * (1.0f/3.0f);
    float y = (sv[3*a+1] + sv[3*b+1] + sv[3*c+1]) * (1.0f/3.0f);
    float z = (sv[3*a+2] + sv[3*b+2] + sv[3*c+2]) * (1.0f/3.0f);
    (ws4 + F4_SB)[i] = make_float4(x, y, z, fmaf(x, x, fmaf(y, y, z*z)));
  }
  if (i < N_V) { // packed vertices (rev targets)
    float x = ov[3*i], y = ov[3*i+1], z = ov[3*i+2];
    pack_target(x, y, z, fmaf(x, x, fmaf(y, y, z*z)),
                (half8*)(ws4 + F4_PKV), i >> 5, i & 31);
  }
  if (i < N_F) { // packed orig barycenters (fwd targets)
    int a = of[3*i], b = of[3*i+1], c = of[3*i+2];
    float x = (ov[3*a] + ov[3*b] + ov[3*c]) * (1.0f/3.0f);
    float y = (ov[3*a+1] + ov[3*b+1] + ov[3*c+1]) * (1.0f/3.0f);
    float z = (ov[3*a+2] + ov[3*b+2] + ov[3*c+2]) * (1.0f/3.0f);
    pack_target(x, y, z, fmaf(x, x, fmaf(y, y, z*z)),
                (half8*)(ws4 + F4_PKO), i >> 5, i & 31);
  }
}

// MFMA min-distance kernel, LDS-staged — the round-7-measured structure
// (best: 102.7 us rev, absmax 0) with ONE change: occupancy.
// launch_bounds(256,5) -> 5 blocks/CU resident (LDS 32KB allows 5/CU; VGPR
// cap 102 >= the 64 this code uses).  Round-7 ran at 3 blocks/CU and spent
// ~50 us in neither-pipe stalls (ds_read latency, nop shadows, barrier
// drains) that co-resident waves can fill (m114 co-scheduling).
__global__ __launch_bounds__(256, 5) void k_min(const float4* __restrict__ q4,
                                                const half8* __restrict__ pk,
                                                unsigned int* __restrict__ minU,
                                                int nchunks) {
  __shared__ half8 sB[TILES * 64];   // 32 KB
  int lane  = threadIdx.x & 63;
  int wave  = threadIdx.x >> 6;
  int half_ = lane >> 5;
  int m     = lane & 31;
  int qbase = blockIdx.x * 256 + wave * (32 * MB);
  int tbase = blockIdx.y * nchunks * TILES;

  // A fragments (validated): A[m=lane&31][k=(lane>>5)*8+j]
  // half0: (p_hi,1, p_hi,1)   half1: (p_lo,0, 0,0,0,0)
  half8 afrag[MB];
  float psq[MB];
  #pragma unroll
  for (int mb = 0; mb < MB; ++mb) {
    float4 q = q4[qbase + mb*32 + m];
    psq[mb] = q.w;
    _Float16 hx = (_Float16)q.x, hy = (_Float16)q.y, hz = (_Float16)q.z;
    half8 a;
    if (half_ == 0) {
      a[0]=hx; a[1]=hy; a[2]=hz; a[3]=(_Float16)1.0f;
      a[4]=hx; a[5]=hy; a[6]=hz; a[7]=(_Float16)1.0f;
    } else {
      a[0]=(_Float16)(q.x-(float)hx); a[1]=(_Float16)(q.y-(float)hy);
      a[2]=(_Float16)(q.z-(float)hz); a[3]=(_Float16)0.0f;
      a[4]=(_Float16)0.0f; a[5]=(_Float16)0.0f; a[6]=(_Float16)0.0f; a[7]=(_Float16)0.0f;
    }
    afrag[mb] = a;
  }

  float inf = __uint_as_float(0x7f800000u);
  float rm0[16], rm1[16];
  #pragma unroll
  for (int r = 0; r < 16; ++r) { rm0[r] = inf; rm1[r] = inf; }

  for (int ch = 0; ch < nchunks; ++ch) {
    int t0 = tbase + ch * TILES;
    if (ch > 0) __syncthreads();   // prior sweep done before overwriting sB
    // async stage: wave w loads tiles w, w+4, ..., w+28 (1 KB each, lane*16B)
    const half8* src = pk + (size_t)(t0 + wave) * 64 + lane;
    #pragma unroll
    for (int j = 0; j < TILES/4; ++j) {
      __builtin_amdgcn_global_load_lds(
          (const __attribute__((address_space(1))) unsigned int*)(src + (size_t)j*256),
          (__attribute__((address_space(3))) unsigned int*)&sB[(wave + 4*j) * 64],
          16, 0, 0);
    }
    __syncthreads();               // vmcnt(0) drained -> tiles resident

    #pragma unroll
    for (int t = 0; t < TILES; t += 2) {
      half8 cA = sB[t*64 + lane];        // ds_read_b128, conflict-free
      half8 cB = sB[t*64 + 64 + lane];
      f32x16 dA, dB, eA, eB;
      mfma4(afrag[0], afrag[1], cA, cB, dA, dB, eA, eB);
      #pragma unroll
      for (int r = 0; r < 16; ++r)
        rm0[r] = fminf(fminf(rm0[r], dA[r]), dB[r]);   // v_min3_f32
      #pragma unroll
      for (int r = 0; r < 16; ++r)
        rm1[r] = fminf(fminf(rm1[r], eA[r]), eB[r]);
    }
  }

  // min across 32 target-columns; write from lane m == row (no q4 reload).
  // C/D: col=lane&31, row=(reg&3)+8*(reg>>2)+4*(lane>>5)   (validated)
  #pragma unroll
  for (int mb = 0; mb < MB; ++mb) {
    float* rm = (mb == 0) ? rm0 : rm1;
    #pragma unroll
    for (int r = 0; r < 16; ++r) {
      float v = rm[r];
      v = fminf(v, __shfl_xor(v, 1, 64));
      v = fminf(v, __shfl_xor(v, 2, 64));
      v = fminf(v, __shfl_xor(v, 4, 64));
      v = fminf(v, __shfl_xor(v, 8, 64));
      v = fminf(v, __shfl_xor(v, 16, 64));
      int row = (r & 3) + 8*(r >> 2) + 4*half_;
      if (m == row) {
        float d2 = fmaxf(psq[mb] + v, 0.0f);
        atomicMin(&minU[qbase + mb*32 + m], __float_as_uint(d2));
      }
    }
  }
}

__device__ __forceinline__ float waveSum(float v) {
  #pragma unroll
  for (int o = 32; o > 0; o >>= 1) v += __shfl_down(v, o, 64);
  return v;
}
__device__ __forceinline__ float waveMax(float v) {
  #pragma unroll
  for (int o = 32; o > 0; o >>= 1) v = fmaxf(v, __shfl_down(v, o, 64));
  return v;
}

__global__ void k_reduce(const float* __restrict__ probs, const float* __restrict__ minf,
                         const float* __restrict__ minr, float* __restrict__ acc) {
  int tid = blockIdx.x * blockDim.x + threadIdx.x;
  int stride = gridDim.x * blockDim.x;
  float sf = 0.0f, sr = 0.0f, mx = 0.0f;
  for (int i = tid; i < NPTS; i += stride) {
    float d = sqrtf(fmaxf(minr[i], 1e-12f));
    sr = fmaf(probs[i >> 4], d, sr);
    mx = fmaxf(mx, d);
    if (i < G_F) {
      float df = sqrtf(fmaxf(minf[i], 1e-12f));
      sf = fmaf(probs[i], df, sf);
      sf = fmaf(1e-4f, 1.0f - probs[i], sf);
    }
  }
  __shared__ float lf[4], lr[4], lm[4];
  int lane = threadIdx.x & 63, wid = threadIdx.x >> 6;
  sf = waveSum(sf); sr = waveSum(sr); mx = waveMax(mx);
  if (lane == 0) { lf[wid] = sf; lr[wid] = sr; lm[wid] = mx; }
  __syncthreads();
  if (wid == 0) {
    float a = (lane < 4) ? lf[lane] : 0.0f;
    float b = (lane < 4) ? lr[lane] : 0.0f;
    float c = (lane < 4) ? lm[lane] : 0.0f;
    a = waveSum(a); b = waveSum(b); c = waveMax(c);
    if (lane == 0) {
      atomicAdd(&acc[0], a);
      atomicAdd(&acc[1], b);
      atomicMax((unsigned int*)&acc[2], __float_as_uint(c));
    }
  }
}

__global__ void k_final(const float* __restrict__ acc, float* __restrict__ out) {
  float maxd = acc[2] + 1e-8f;
  out[0] = acc[0] + acc[1] * 0.1f / maxd;
}

extern "C" void kernel_launch(void* const* d_in, const int* in_sizes, int n_in,
                              void* d_out, int out_size, void* d_ws, size_t ws_size,
                              hipStream_t stream) {
  const float* ov    = (const float*)d_in[0];
  const int*   of    = (const int*)  d_in[1];
  const float* sv    = (const float*)d_in[2];
  const int*   sfc   = (const int*)  d_in[3];
  const float* probs = (const float*)d_in[4];
  const float* r1    = (const float*)d_in[5];
  const float* r2    = (const float*)d_in[6];
  float*  ws  = (float*)d_ws;
  float4* ws4 = (float4*)d_ws;
  float*  out = (float*)d_out;

  float*        acc   = ws;
  float4*       sb4   = ws4 + F4_SB;
  float4*       pts4  = ws4 + F4_PTS;
  half8*        pkV   = (half8*)(ws4 + F4_PKV);
  half8*        pkO   = (half8*)(ws4 + F4_PKO);
  unsigned int* minfU = (unsigned int*)(ws + WS_MINF);
  unsigned int* minrU = (unsigned int*)(ws + WS_MINR);
  const float*  minfF = ws + WS_MINF;
  const float*  minrF = ws + WS_MINR;

  k_prep<<<NPTS/256, 256, 0, stream>>>(ov, of, sv, sfc, r1, r2,
                                       (unsigned int*)ws, ws4);
  // fwd: 8192 queries, 512 obary tiles; 32 x 16 blocks, 1 chunk each
  k_min<<<dim3(G_F/256, 16), 256, 0, stream>>>(sb4, pkO, minfU, 1);
  // rev: 131072 queries, 512 vert tiles; 512 x 16 blocks, 1 chunk each
  // (ksplit 16: one stage+sweep per block, finer interleave, 2.1M atomics
  //  over 131k addresses — negligible)
  k_min<<<dim3(NPTS/256, 16), 256, 0, stream>>>(pts4, pkV, minrU, 1);
  k_reduce<<<256, 256, 0, stream>>>(probs, minfF, minrF, acc);
  k_final<<<1, 1, 0, stream>>>(acc, out);
}

// Round 12
// 188.601 us; speedup vs baseline: 3.8530x; 3.8530x over previous
//
#include <hip/hip_runtime.h>
#include <math.h>

// Problem sizes (fixed by setup_inputs)
constexpr int N_V  = 16384;       // original vertices
constexpr int N_F  = 16384;       // original faces (targets for fwd)
constexpr int G_F  = 8192;        // simplified faces (queries for fwd)
constexpr int NS   = 16;          // samples per face
constexpr int NPTS = G_F * NS;    // 131072 sample points (queries for rev)

constexpr int MB    = 2;          // 32-row query blocks per wave (64 queries/wave)
constexpr int TILES = 32;         // B-tiles staged per LDS chunk (32 KB)

typedef _Float16 half8 __attribute__((ext_vector_type(8)));

// ---------------- workspace layout (float4 units first, 16B aligned) ----------
constexpr int F4_ACC   = 0;                    // 1  float4: accumulators
constexpr int F4_SB    = 1;                    // [G_F]  simp barycenters x,y,z,|b|^2
constexpr int F4_PTS   = F4_SB + G_F;          // [NPTS] sample points    x,y,z,|p|^2
constexpr int F4_PKV   = F4_PTS + NPTS;        // packed verts: 512 tiles * 64 * 16B
constexpr int F4_PKO   = F4_PKV + 32768;       // packed obary: 512 tiles * 64 * 16B
constexpr int F4_TOTAL = F4_PKO + 32768;
constexpr int WS_MINF  = F4_TOTAL * 4;         // [G_F]  fwd min d^2 (uint bits)
constexpr int WS_MINR  = WS_MINF + G_F;        // [NPTS] rev min d^2 (uint bits)

// ---- monolithic chunk-sweep asm -------------------------------------------
// Entire 32-tile sweep in ONE asm block: rm lives in 32 "+v" operands (arch
// VGPRs, copied at most once per chunk — the AGPR churn that cost ~50 us/
// round in rounds 7-10 cannot occur inside the block).  MFMA dsts pinned via
// clobbers v[32:95]; B-tiles ping-pong in v[96:111] via explicit ds_read.
// Per iteration: 4 MFMA -> prefetch next tile-pair -> 5x s_nop 7 (+2 ds_read
// issue ~= the round-6/7-proven 48-cycle MFMA->VALU hazard pad) -> 32
// v_min3_f32 -> s_waitcnt.  d-reg WAR across iterations is safe: VALU reads
// at issue, before the next iteration's MFMAs issue.
#define MIN32 \
  "v_min3_f32 %0, %0, v32, v48\n\t"   "v_min3_f32 %1, %1, v33, v49\n\t"   \
  "v_min3_f32 %2, %2, v34, v50\n\t"   "v_min3_f32 %3, %3, v35, v51\n\t"   \
  "v_min3_f32 %4, %4, v36, v52\n\t"   "v_min3_f32 %5, %5, v37, v53\n\t"   \
  "v_min3_f32 %6, %6, v38, v54\n\t"   "v_min3_f32 %7, %7, v39, v55\n\t"   \
  "v_min3_f32 %8, %8, v40, v56\n\t"   "v_min3_f32 %9, %9, v41, v57\n\t"   \
  "v_min3_f32 %10, %10, v42, v58\n\t" "v_min3_f32 %11, %11, v43, v59\n\t" \
  "v_min3_f32 %12, %12, v44, v60\n\t" "v_min3_f32 %13, %13, v45, v61\n\t" \
  "v_min3_f32 %14, %14, v46, v62\n\t" "v_min3_f32 %15, %15, v47, v63\n\t" \
  "v_min3_f32 %16, %16, v64, v80\n\t" "v_min3_f32 %17, %17, v65, v81\n\t" \
  "v_min3_f32 %18, %18, v66, v82\n\t" "v_min3_f32 %19, %19, v67, v83\n\t" \
  "v_min3_f32 %20, %20, v68, v84\n\t" "v_min3_f32 %21, %21, v69, v85\n\t" \
  "v_min3_f32 %22, %22, v70, v86\n\t" "v_min3_f32 %23, %23, v71, v87\n\t" \
  "v_min3_f32 %24, %24, v72, v88\n\t" "v_min3_f32 %25, %25, v73, v89\n\t" \
  "v_min3_f32 %26, %26, v74, v90\n\t" "v_min3_f32 %27, %27, v75, v91\n\t" \
  "v_min3_f32 %28, %28, v76, v92\n\t" "v_min3_f32 %29, %29, v77, v93\n\t" \
  "v_min3_f32 %30, %30, v78, v94\n\t" "v_min3_f32 %31, %31, v79, v95\n\t"

#define ITER_E(O0, O1) \
  "v_mfma_f32_32x32x16_f16 v[32:47], %32, v[96:99], 0\n\t"    \
  "v_mfma_f32_32x32x16_f16 v[48:63], %32, v[100:103], 0\n\t"  \
  "v_mfma_f32_32x32x16_f16 v[64:79], %33, v[96:99], 0\n\t"    \
  "v_mfma_f32_32x32x16_f16 v[80:95], %33, v[100:103], 0\n\t"  \
  "ds_read_b128 v[104:107], %34 offset:" O0 "\n\t"            \
  "ds_read_b128 v[108:111], %34 offset:" O1 "\n\t"            \
  "s_nop 7\n\ts_nop 7\n\ts_nop 7\n\ts_nop 7\n\ts_nop 7\n\t"   \
  MIN32                                                       \
  "s_waitcnt lgkmcnt(0)\n\t"

#define ITER_O(O0, O1) \
  "v_mfma_f32_32x32x16_f16 v[32:47], %32, v[104:107], 0\n\t"  \
  "v_mfma_f32_32x32x16_f16 v[48:63], %32, v[108:111], 0\n\t"  \
  "v_mfma_f32_32x32x16_f16 v[64:79], %33, v[104:107], 0\n\t"  \
  "v_mfma_f32_32x32x16_f16 v[80:95], %33, v[108:111], 0\n\t"  \
  "ds_read_b128 v[96:99], %34 offset:" O0 "\n\t"              \
  "ds_read_b128 v[100:103], %34 offset:" O1 "\n\t"            \
  "s_nop 7\n\ts_nop 7\n\ts_nop 7\n\ts_nop 7\n\ts_nop 7\n\t"   \
  MIN32                                                       \
  "s_waitcnt lgkmcnt(0)\n\t"

#define SWEEP32(RM0, RM1, A0, A1, ADDR)                                     \
  asm volatile(                                                             \
    "ds_read_b128 v[96:99], %34 offset:0\n\t"                               \
    "ds_read_b128 v[100:103], %34 offset:1024\n\t"                          \
    "s_waitcnt lgkmcnt(0)\n\t"                                              \
    ITER_E("2048","3072")   ITER_O("4096","5120")                           \
    ITER_E("6144","7168")   ITER_O("8192","9216")                           \
    ITER_E("10240","11264") ITER_O("12288","13312")                         \
    ITER_E("14336","15360") ITER_O("16384","17408")                         \
    ITER_E("18432","19456") ITER_O("20480","21504")                         \
    ITER_E("22528","23552") ITER_O("24576","25600")                         \
    ITER_E("26624","27648") ITER_O("28672","29696")                         \
    ITER_E("30720","31744") ITER_O("0","1024")                              \
    : "+v"(RM0[0]),  "+v"(RM0[1]),  "+v"(RM0[2]),  "+v"(RM0[3]),            \
      "+v"(RM0[4]),  "+v"(RM0[5]),  "+v"(RM0[6]),  "+v"(RM0[7]),            \
      "+v"(RM0[8]),  "+v"(RM0[9]),  "+v"(RM0[10]), "+v"(RM0[11]),           \
      "+v"(RM0[12]), "+v"(RM0[13]), "+v"(RM0[14]), "+v"(RM0[15]),           \
      "+v"(RM1[0]),  "+v"(RM1[1]),  "+v"(RM1[2]),  "+v"(RM1[3]),            \
      "+v"(RM1[4]),  "+v"(RM1[5]),  "+v"(RM1[6]),  "+v"(RM1[7]),            \
      "+v"(RM1[8]),  "+v"(RM1[9]),  "+v"(RM1[10]), "+v"(RM1[11]),           \
      "+v"(RM1[12]), "+v"(RM1[13]), "+v"(RM1[14]), "+v"(RM1[15])            \
    : "v"(A0), "v"(A1), "v"(ADDR)                                           \
    : "v32","v33","v34","v35","v36","v37","v38","v39",                      \
      "v40","v41","v42","v43","v44","v45","v46","v47",                      \
      "v48","v49","v50","v51","v52","v53","v54","v55",                      \
      "v56","v57","v58","v59","v60","v61","v62","v63",                      \
      "v64","v65","v66","v67","v68","v69","v70","v71",                      \
      "v72","v73","v74","v75","v76","v77","v78","v79",                      \
      "v80","v81","v82","v83","v84","v85","v86","v87",                      \
      "v88","v89","v90","v91","v92","v93","v94","v95",                      \
      "v96","v97","v98","v99","v100","v101","v102","v103",                  \
      "v104","v105","v106","v107","v108","v109","v110","v111",              \
      "memory")

// Pack one target (x,y,z,sq) into B-fragment order (validated: absmax=0):
// col n = lane&31, k = (lane>>5)*8 + j.
// k0-3 = hi(-2x,-2y,-2z,|v|^2), k4-7 = lo residuals, k8-11 = hi again, k12-15 = 0.
__device__ __forceinline__ void pack_target(float x, float y, float z, float sq,
                                            half8* __restrict__ pk, int tile, int n) {
  float ax = -2.0f*x, ay = -2.0f*y, az = -2.0f*z;
  _Float16 hx = (_Float16)ax, hy = (_Float16)ay, hz = (_Float16)az, hw = (_Float16)sq;
  _Float16 lx = (_Float16)(ax - (float)hx), ly = (_Float16)(ay - (float)hy);
  _Float16 lz = (_Float16)(az - (float)hz), lw = (_Float16)(sq - (float)hw);
  half8 h0; h0[0]=hx; h0[1]=hy; h0[2]=hz; h0[3]=hw; h0[4]=lx; h0[5]=ly; h0[6]=lz; h0[7]=lw;
  half8 h1; h1[0]=hx; h1[1]=hy; h1[2]=hz; h1[3]=hw;
  h1[4]=(_Float16)0.0f; h1[5]=(_Float16)0.0f; h1[6]=(_Float16)0.0f; h1[7]=(_Float16)0.0f;
  pk[(size_t)tile*64 + n]      = h0;
  pk[(size_t)tile*64 + 32 + n] = h1;
}

// Fused prep, one thread per sample point.
__global__ void k_prep(const float* __restrict__ ov, const int* __restrict__ of,
                       const float* __restrict__ sv, const int* __restrict__ sf,
                       const float* __restrict__ r1, const float* __restrict__ r2,
                       unsigned int* __restrict__ ws, float4* __restrict__ ws4) {
  int i = blockIdx.x * blockDim.x + threadIdx.x;
  if (i < 4) ws[i] = 0u;                          // acc = 0.0f
  ws[WS_MINR + i] = 0x7f800000u;                  // +inf (grid == NPTS exactly)

  { // sample point i (face verts are 96 KB total -> L1/L2-hot gathers)
    int g = i >> 4;
    int a = sf[3*g], b = sf[3*g+1], c = sf[3*g+2];
    float sr = sqrtf(r1[i]);
    float u = 1.0f - sr;
    float v = sr * (1.0f - r2[i]);
    float w = sr * r2[i];
    float px = u*sv[3*a]   + v*sv[3*b]   + w*sv[3*c];
    float py = u*sv[3*a+1] + v*sv[3*b+1] + w*sv[3*c+1];
    float pz = u*sv[3*a+2] + v*sv[3*b+2] + w*sv[3*c+2];
    (ws4 + F4_PTS)[i] = make_float4(px, py, pz, fmaf(px, px, fmaf(py, py, pz*pz)));
  }
  if (i < G_F) { // simp barycenter (fwd query) + minf init
    ws[WS_MINF + i] = 0x7f800000u;
    int a = sf[3*i], b = sf[3*i+1], c = sf[3*i+2];
    float x = (sv[3*a] + sv[3*b] + sv[3*c]) * (1.0f/3.0f);
    float y = (sv[3*a+1] + sv[3*b+1] + sv[3*c+1]) * (1.0f/3.0f);
    float z = (sv[3*a+2] + sv[3*b+2] + sv[3*c+2]) * (1.0f/3.0f);
    (ws4 + F4_SB)[i] = make_float4(x, y, z, fmaf(x, x, fmaf(y, y, z*z)));
  }
  if (i < N_V) { // packed vertices (rev targets)
    float x = ov[3*i], y = ov[3*i+1], z = ov[3*i+2];
    pack_target(x, y, z, fmaf(x, x, fmaf(y, y, z*z)),
                (half8*)(ws4 + F4_PKV), i >> 5, i & 31);
  }
  if (i < N_F) { // packed orig barycenters (fwd targets)
    int a = of[3*i], b = of[3*i+1], c = of[3*i+2];
    float x = (ov[3*a] + ov[3*b] + ov[3*c]) * (1.0f/3.0f);
    float y = (ov[3*a+1] + ov[3*b+1] + ov[3*c+1]) * (1.0f/3.0f);
    float z = (ov[3*a+2] + ov[3*b+2] + ov[3*c+2]) * (1.0f/3.0f);
    pack_target(x, y, z, fmaf(x, x, fmaf(y, y, z*z)),
                (half8*)(ws4 + F4_PKO), i >> 5, i & 31);
  }
}

// MFMA min-distance kernel, LDS-staged — round-7 structure (grids, bounds,
// staging) with the monolithic SWEEP32 asm replacing the mfma4+fminf loop.
// launch_bounds(256,3): forced arch usage ~140 <= 168 cap — NO spill (round
// 11 lesson: (256,5) cap 96 -> 2.4 GB scratch traffic, 6x regression).
__global__ __launch_bounds__(256, 3) void k_min(const float4* __restrict__ q4,
                                                const half8* __restrict__ pk,
                                                unsigned int* __restrict__ minU,
                                                int nchunks) {
  __shared__ half8 sB[TILES * 64];   // 32 KB
  int lane  = threadIdx.x & 63;
  int wave  = threadIdx.x >> 6;
  int half_ = lane >> 5;
  int m     = lane & 31;
  int qbase = blockIdx.x * 256 + wave * (32 * MB);
  int tbase = blockIdx.y * nchunks * TILES;

  // A fragments (validated): A[m=lane&31][k=(lane>>5)*8+j]
  // half0: (p_hi,1, p_hi,1)   half1: (p_lo,0, 0,0,0,0)
  half8 afrag[MB];
  float psq[MB];
  #pragma unroll
  for (int mb = 0; mb < MB; ++mb) {
    float4 q = q4[qbase + mb*32 + m];
    psq[mb] = q.w;
    _Float16 hx = (_Float16)q.x, hy = (_Float16)q.y, hz = (_Float16)q.z;
    half8 a;
    if (half_ == 0) {
      a[0]=hx; a[1]=hy; a[2]=hz; a[3]=(_Float16)1.0f;
      a[4]=hx; a[5]=hy; a[6]=hz; a[7]=(_Float16)1.0f;
    } else {
      a[0]=(_Float16)(q.x-(float)hx); a[1]=(_Float16)(q.y-(float)hy);
      a[2]=(_Float16)(q.z-(float)hz); a[3]=(_Float16)0.0f;
      a[4]=(_Float16)0.0f; a[5]=(_Float16)0.0f; a[6]=(_Float16)0.0f; a[7]=(_Float16)0.0f;
    }
    afrag[mb] = a;
  }

  // LDS byte address of this lane's fragment slot (raw AS(3) offset)
  unsigned lAddr = (unsigned)(size_t)
      (__attribute__((address_space(3))) char*)&sB[lane];

  float inf = __uint_as_float(0x7f800000u);
  float rm0[16], rm1[16];
  #pragma unroll
  for (int r = 0; r < 16; ++r) { rm0[r] = inf; rm1[r] = inf; }

  for (int ch = 0; ch < nchunks; ++ch) {
    int t0 = tbase + ch * TILES;
    if (ch > 0) __syncthreads();   // prior sweep done before overwriting sB
    // async stage: wave w loads tiles w, w+4, ..., w+28 (1 KB each, lane*16B)
    const half8* src = pk + (size_t)(t0 + wave) * 64 + lane;
    #pragma unroll
    for (int j = 0; j < TILES/4; ++j) {
      __builtin_amdgcn_global_load_lds(
          (const __attribute__((address_space(1))) unsigned int*)(src + (size_t)j*256),
          (__attribute__((address_space(3))) unsigned int*)&sB[(wave + 4*j) * 64],
          16, 0, 0);
    }
    __syncthreads();               // vmcnt(0) drained -> tiles resident

    SWEEP32(rm0, rm1, afrag[0], afrag[1], lAddr);
  }

  // min across 32 target-columns; write from lane m == row (no q4 reload).
  // C/D: col=lane&31, row=(reg&3)+8*(reg>>2)+4*(lane>>5)   (validated)
  #pragma unroll
  for (int mb = 0; mb < MB; ++mb) {
    float* rm = (mb == 0) ? rm0 : rm1;
    #pragma unroll
    for (int r = 0; r < 16; ++r) {
      float v = rm[r];
      v = fminf(v, __shfl_xor(v, 1, 64));
      v = fminf(v, __shfl_xor(v, 2, 64));
      v = fminf(v, __shfl_xor(v, 4, 64));
      v = fminf(v, __shfl_xor(v, 8, 64));
      v = fminf(v, __shfl_xor(v, 16, 64));
      int row = (r & 3) + 8*(r >> 2) + 4*half_;
      if (m == row) {
        float d2 = fmaxf(psq[mb] + v, 0.0f);
        atomicMin(&minU[qbase + mb*32 + m], __float_as_uint(d2));
      }
    }
  }
}

__device__ __forceinline__ float waveSum(float v) {
  #pragma unroll
  for (int o = 32; o > 0; o >>= 1) v += __shfl_down(v, o, 64);
  return v;
}
__device__ __forceinline__ float waveMax(float v) {
  #pragma unroll
  for (int o = 32; o > 0; o >>= 1) v = fmaxf(v, __shfl_down(v, o, 64));
  return v;
}

__global__ void k_reduce(const float* __restrict__ probs, const float* __restrict__ minf,
                         const float* __restrict__ minr, float* __restrict__ acc) {
  int tid = blockIdx.x * blockDim.x + threadIdx.x;
  int stride = gridDim.x * blockDim.x;
  float sf = 0.0f, sr = 0.0f, mx = 0.0f;
  for (int i = tid; i < NPTS; i += stride) {
    float d = sqrtf(fmaxf(minr[i], 1e-12f));
    sr = fmaf(probs[i >> 4], d, sr);
    mx = fmaxf(mx, d);
    if (i < G_F) {
      float df = sqrtf(fmaxf(minf[i], 1e-12f));
      sf = fmaf(probs[i], df, sf);
      sf = fmaf(1e-4f, 1.0f - probs[i], sf);
    }
  }
  __shared__ float lf[4], lr[4], lm[4];
  int lane = threadIdx.x & 63, wid = threadIdx.x >> 6;
  sf = waveSum(sf); sr = waveSum(sr); mx = waveMax(mx);
  if (lane == 0) { lf[wid] = sf; lr[wid] = sr; lm[wid] = mx; }
  __syncthreads();
  if (wid == 0) {
    float a = (lane < 4) ? lf[lane] : 0.0f;
    float b = (lane < 4) ? lr[lane] : 0.0f;
    float c = (lane < 4) ? lm[lane] : 0.0f;
    a = waveSum(a); b = waveSum(b); c = waveMax(c);
    if (lane == 0) {
      atomicAdd(&acc[0], a);
      atomicAdd(&acc[1], b);
      atomicMax((unsigned int*)&acc[2], __float_as_uint(c));
    }
  }
}

__global__ void k_final(const float* __restrict__ acc, float* __restrict__ out) {
  float maxd = acc[2] + 1e-8f;
  out[0] = acc[0] + acc[1] * 0.1f / maxd;
}

extern "C" void kernel_launch(void* const* d_in, const int* in_sizes, int n_in,
                              void* d_out, int out_size, void* d_ws, size_t ws_size,
                              hipStream_t stream) {
  const float* ov    = (const float*)d_in[0];
  const int*   of    = (const int*)  d_in[1];
  const float* sv    = (const float*)d_in[2];
  const int*   sfc   = (const int*)  d_in[3];
  const float* probs = (const float*)d_in[4];
  const float* r1    = (const float*)d_in[5];
  const float* r2    = (const float*)d_in[6];
  float*  ws  = (float*)d_ws;
  float4* ws4 = (float4*)d_ws;
  float*  out = (float*)d_out;

  float*        acc   = ws;
  float4*       sb4   = ws4 + F4_SB;
  float4*       pts4  = ws4 + F4_PTS;
  half8*        pkV   = (half8*)(ws4 + F4_PKV);
  half8*        pkO   = (half8*)(ws4 + F4_PKO);
  unsigned int* minfU = (unsigned int*)(ws + WS_MINF);
  unsigned int* minrU = (unsigned int*)(ws + WS_MINR);
  const float*  minfF = ws + WS_MINF;
  const float*  minrF = ws + WS_MINR;

  k_prep<<<NPTS/256, 256, 0, stream>>>(ov, of, sv, sfc, r1, r2,
                                       (unsigned int*)ws, ws4);
  // fwd: 8192 queries, 512 obary tiles; 32 x 16 blocks, 1 chunk each
  k_min<<<dim3(G_F/256, 16), 256, 0, stream>>>(sb4, pkO, minfU, 1);
  // rev: 131072 queries, 512 vert tiles; 512 x 8 blocks, 2 chunks each
  k_min<<<dim3(NPTS/256, 8), 256, 0, stream>>>(pts4, pkV, minrU, 2);
  k_reduce<<<256, 256, 0, stream>>>(probs, minfF, minrF, acc);
  k_final<<<1, 1, 0, stream>>>(acc, out);
}